// Round 5
// baseline (104.071 us; speedup 1.0000x reference)
//
#include <hip/hip_runtime.h>
#include <stdint.h>

#define K_ELL 32      // ELL planes per near/far array (column-major)
#define K_OVF 16      // overflow planes (out-of-band fallback, expected ~empty)
#define RNG   2048    // band quantum: window base = a & ~(RNG-1)
#define RW    (RNG + RNG)    // in-band limit on rel -> |u - nbr| <= 4096
#define BB    256     // build block size
#define UA    6       // unrolled a-side slots
#define UN    6       // unrolled near-ELL slots
#define UF    4       // unrolled far-ELL slots
#define GBS   1024    // staged gather block (vertices per block)
#define HALO  4096    // band invariant: in-band |u - nbr| <= 4096
#define SPAN  (GBS + 2 * HALO)          // 9216 float4 = 147456 B = 144 KiB LDS
#define SMEM_STG (SPAN * (int)sizeof(float4))

// build: one balanced grid-stride kernel. Edge scatter uses GLOBAL atomic ranks
// on pre-zeroed cntN/cntF/deg_ovf (hipMemsetAsync) -> no windows, no LDS, no
// prep kernel. Also builds offs_a, faces->float (int4/float4), v->float4 repack.
__global__ __launch_bounds__(BB) void build_kernel(
        const int2* __restrict__ edges, int* __restrict__ offs_a,
        int* __restrict__ cntN, int* __restrict__ cntF, int* __restrict__ deg_ovf,
        int* __restrict__ adjN, int* __restrict__ adjF, int* __restrict__ adj_ovf,
        const int* __restrict__ faces, float* __restrict__ out_f,
        const float* __restrict__ v, float4* __restrict__ v4,
        int E, int V, int F3) {
    const int t = (int)blockIdx.x * BB + (int)threadIdx.x;
    const int T = (int)gridDim.x * BB;
    // ---- edge scatter: rank = global atomic on zeroed counters ----
    for (int i = t; i < E; i += T) {
        int2 e = edges[i];
        int rel = e.y - (e.x & ~(RNG - 1)) - 1;      // b > a -> rel >= 0
        if (rel < RNG) {
            int r = atomicAdd(&cntN[e.y], 1);
            if (r < K_ELL) adjN[(size_t)r * V + e.y] = e.x;
        } else if (rel < RW) {
            int r = atomicAdd(&cntF[e.y], 1);
            if (r < K_ELL) adjF[(size_t)r * V + e.y] = e.x;
        } else {                                     // rare out-of-band
            int r = atomicAdd(&deg_ovf[e.y], 1);
            if (r < K_OVF) adj_ovf[(size_t)r * V + e.y] = e.x;
        }
    }
    // ---- offs_a[u] = first edge with .x >= u (edges[:,0] sorted asc) ----
    for (int i = t; i <= E; i += T) {
        if (i < E) {
            int lo = (i == 0) ? 0 : edges[i - 1].x + 1;
            int hi = edges[i].x;
            for (int a = lo; a <= hi; ++a) offs_a[a] = i;
        } else {
            int lo = (E > 0) ? edges[E - 1].x + 1 : 0;
            for (int a = lo; a <= V; ++a) offs_a[a] = E;
        }
    }
    // ---- faces -> float (vectorized) ----
    if ((((uintptr_t)out_f | (uintptr_t)faces) & 15) == 0) {
        int n4 = F3 >> 2;
        const int4* f4 = (const int4*)faces;
        float4* o4 = (float4*)out_f;
        for (int j = t; j < n4; j += T) {
            int4 a = f4[j];
            o4[j] = make_float4((float)a.x, (float)a.y, (float)a.z, (float)a.w);
        }
        for (int j = (n4 << 2) + t; j < F3; j += T) out_f[j] = (float)faces[j];
    } else {
        for (int j = t; j < F3; j += T) out_f[j] = (float)faces[j];
    }
    // ---- v[V,3] -> v4[V] float4 repack (vectorized) ----
    if (((uintptr_t)v & 15) == 0) {
        const float4* vv = (const float4*)v;
        int n4v = V >> 2;
        for (int q = t; q < n4v; q += T) {           // 3x float4 in -> 4x out
            float4 a = vv[3 * q], b = vv[3 * q + 1], c = vv[3 * q + 2];
            v4[4 * q + 0] = make_float4(a.x, a.y, a.z, 0.f);
            v4[4 * q + 1] = make_float4(a.w, b.x, b.y, 0.f);
            v4[4 * q + 2] = make_float4(b.z, b.w, c.x, 0.f);
            v4[4 * q + 3] = make_float4(c.y, c.z, c.w, 0.f);
        }
        for (int u = (n4v << 2) + t; u < V; u += T)
            v4[u] = make_float4(v[3 * u], v[3 * u + 1], v[3 * u + 2], 0.f);
    } else {
        for (int u = t; u < V; u += T)
            v4[u] = make_float4(v[3 * u], v[3 * u + 1], v[3 * u + 2], 0.f);
    }
}

// staged gather: block stages x4 band [c0-HALO, c0+GBS+HALO) into LDS
// (coalesced), so every in-band value fetch (|u - nbr| <= 4096 by band
// construction) is an LDS read instead of a 64-lane-divergent L2 line.
// Any index outside the staged span (a-side long edges, overflow) falls back
// to global via the unsigned range check -> always correct.
template <bool PAD>
__global__ __launch_bounds__(GBS) void gather_staged(
        const float4* __restrict__ x4, const int2* __restrict__ edges,
        const int* __restrict__ offs_a,
        const int* __restrict__ cntN, const int* __restrict__ cntF,
        const int* __restrict__ deg_ovf,
        const int* __restrict__ adjN, const int* __restrict__ adjF,
        const int* __restrict__ adj_ovf,
        float* __restrict__ y, int V, int E) {
    extern __shared__ float4 tile[];
    const int c0   = (int)blockIdx.x * GBS;
    const int base = c0 - HALO;
    const int u    = c0 + (int)threadIdx.x;
    // metadata + index loads first (independent of staging -> overlap)
    int aBeg = 0, da = 0, cN = 0, cF = 0, dO = 0;
    int gA[UA], gN[UN], gF[UF];
    if (u < V) {
        aBeg = offs_a[u];
        int aEnd = offs_a[u + 1];
        da = aEnd - aBeg;
        cN = cntN[u]; cF = cntF[u]; dO = deg_ovf[u];
        #pragma unroll
        for (int j = 0; j < UA; ++j) gA[j] = edges[min(aBeg + j, E - 1)].y;
        #pragma unroll
        for (int k = 0; k < UN; ++k) gN[k] = adjN[(size_t)k * V + u];
        #pragma unroll
        for (int k = 0; k < UF; ++k) gF[k] = adjF[(size_t)k * V + u];
    }
    // stage the band (coalesced float4)
    for (int s = (int)threadIdx.x; s < SPAN; s += GBS) {
        int g = base + s;
        tile[s] = (g >= 0 && g < V) ? x4[g] : make_float4(0.f, 0.f, 0.f, 0.f);
    }
    __syncthreads();
    if (u >= V) return;
    int kN = cN > K_ELL ? K_ELL : cN;
    int kF = cF > K_ELL ? K_ELL : cF;
    float s0 = 0.f, s1 = 0.f, s2 = 0.f;
    #pragma unroll
    for (int j = 0; j < UA; ++j) {
        int g = (j < da) ? gA[j] : u;                // invalid slot -> self (masked)
        float m = (j < da) ? 1.f : 0.f;
        unsigned r = (unsigned)(g - base);
        float4 p = (r < (unsigned)SPAN) ? tile[r] : x4[g];
        s0 += m * p.x; s1 += m * p.y; s2 += m * p.z;
    }
    for (int j = UA; j < da; ++j) {                  // rare high-valence tail
        float4 p = x4[edges[aBeg + j].y];
        s0 += p.x; s1 += p.y; s2 += p.z;
    }
    #pragma unroll
    for (int k = 0; k < UN; ++k) {
        int g = (k < kN) ? gN[k] : u;
        float m = (k < kN) ? 1.f : 0.f;
        unsigned r = (unsigned)(g - base);
        float4 p = (r < (unsigned)SPAN) ? tile[r] : x4[g];
        s0 += m * p.x; s1 += m * p.y; s2 += m * p.z;
    }
    for (int k = UN; k < kN; ++k) {
        float4 p = x4[adjN[(size_t)k * V + u]];
        s0 += p.x; s1 += p.y; s2 += p.z;
    }
    #pragma unroll
    for (int k = 0; k < UF; ++k) {
        int g = (k < kF) ? gF[k] : u;
        float m = (k < kF) ? 1.f : 0.f;
        unsigned r = (unsigned)(g - base);
        float4 p = (r < (unsigned)SPAN) ? tile[r] : x4[g];
        s0 += m * p.x; s1 += m * p.y; s2 += m * p.z;
    }
    for (int k = UF; k < kF; ++k) {
        float4 p = x4[adjF[(size_t)k * V + u]];
        s0 += p.x; s1 += p.y; s2 += p.z;
    }
    int kO = dO > K_OVF ? K_OVF : dO;
    for (int k = 0; k < kO; ++k) {                   // expected empty
        float4 p = x4[adj_ovf[(size_t)k * V + u]];
        s0 += p.x; s1 += p.y; s2 += p.z;
    }
    int d = da + cN + cF + dO;
    float inv = 1.0f / fmaxf((float)d, 1.0f);
    if (PAD) {
        ((float4*)y)[u] = make_float4(s0 * inv, s1 * inv, s2 * inv, 0.f);
    } else {
        y[3 * u + 0] = s0 * inv;
        y[3 * u + 1] = s1 * inv;
        y[3 * u + 2] = s2 * inv;
    }
}

extern "C" void kernel_launch(void* const* d_in, const int* in_sizes, int n_in,
                              void* d_out, int out_size, void* d_ws, size_t ws_size,
                              hipStream_t stream) {
    const float* v     = (const float*)d_in[0];  // [V,3]
    const int2*  edges = (const int2*)d_in[1];   // [E,2], rows lex-sorted, a<b
    const int*   faces = (const int*)d_in[2];    // [F,3]

    const int V3 = in_sizes[0];
    const int V  = V3 / 3;
    const int E  = in_sizes[1] / 2;
    const int F3 = in_sizes[2];

    float* out_v = (float*)d_out;
    float* out_f = (float*)d_out + V3;

    // ws layout (16B-aligned float4 arrays first): v4[V] | x1[V] | adjN[K_ELL*V] |
    //   adjF[K_ELL*V] | adj_ovf[K_OVF*V] | offs_a[V+1] | cntN[V+1] | cntF[V+1] | deg_ovf[V]
    float4* v4      = (float4*)d_ws;
    float4* x1      = v4 + V;
    int*    adjN    = (int*)(x1 + V);
    int*    adjF    = adjN + (size_t)K_ELL * V;
    int*    adj_ovf = adjF + (size_t)K_ELL * V;
    int*    offs_a  = adj_ovf + (size_t)K_OVF * V;
    int*    cntN    = offs_a + (V + 1);
    int*    cntF    = cntN + (V + 1);
    int*    deg_ovf = cntF + (V + 1);

    // node 1: zero the contiguous cntN|cntF|deg_ovf block (build's atomics need 0)
    (void)hipMemsetAsync(cntN, 0, (size_t)(3 * V + 2) * sizeof(int), stream);

    // node 2: balanced grid-stride build (scatter + offs_a + faces + v4)
    int maxWork = E + 1;
    if (F3 > maxWork) maxWork = F3;
    if (V > maxWork)  maxWork = V;
    int gB = (maxWork + BB - 1) / BB;
    if (gB > 2048) gB = 2048;
    build_kernel<<<gB, BB, 0, stream>>>(edges, offs_a, cntN, cntF, deg_ovf,
                                        adjN, adjF, adj_ovf, faces, out_f,
                                        v, v4, E, V, F3);

    // nodes 3+4: two smoothing rounds (144 KiB dynamic LDS each; <=160 KiB/CU cap,
    // no attribute opt-in needed on ROCm)
    int gS = (V + GBS - 1) / GBS;
    gather_staged<true ><<<gS, GBS, SMEM_STG, stream>>>(
        v4, edges, offs_a, cntN, cntF, deg_ovf, adjN, adjF, adj_ovf,
        (float*)x1, V, E);
    gather_staged<false><<<gS, GBS, SMEM_STG, stream>>>(
        x1, edges, offs_a, cntN, cntF, deg_ovf, adjN, adjF, adj_ovf,
        out_v, V, E);
}

// Round 6
// 97.060 us; speedup vs baseline: 1.0722x; 1.0722x over previous
//
#include <hip/hip_runtime.h>
#include <stdint.h>

#define K_ELL 32      // ELL planes (column-major; plane k touched only if some vertex has rank k)
#define K_OVF 16      // rank-overflow planes (cnt > 32; expected empty)
#define BB    256     // build block size
#define BS    256     // gather block size
#define UA    6       // unrolled a-side slots (index loads hoisted, branchless)
#define UB    6       // unrolled b-side ELL slots

// build: one balanced grid-stride kernel (no windows, no LDS, no prep kernel).
// Edge scatter ranks via GLOBAL atomics on pre-zeroed cnt (hipMemsetAsync):
// vertex u's b-side neighbors land in adj[r*V+u], r = atomic rank; rank >= 32
// spills to ovf planes (count derived from cnt later, no separate counter).
// Also builds offs_a (gather-only), faces->float (int4/float4), v->float4.
__global__ __launch_bounds__(BB) void build_kernel(
        const int2* __restrict__ edges, int* __restrict__ offs_a,
        int* __restrict__ cnt, int* __restrict__ adj, int* __restrict__ ovf,
        const int* __restrict__ faces, float* __restrict__ out_f,
        const float* __restrict__ v, float4* __restrict__ v4,
        int E, int V, int F3) {
    const int t = (int)blockIdx.x * BB + (int)threadIdx.x;
    const int T = (int)gridDim.x * BB;
    // ---- edge scatter: rank = global atomic on zeroed cnt ----
    for (int i = t; i < E; i += T) {
        int2 e = edges[i];
        int r = atomicAdd(&cnt[e.y], 1);
        if (r < K_ELL)              adj[(size_t)r * V + e.y] = e.x;
        else if (r < K_ELL + K_OVF) ovf[(size_t)(r - K_ELL) * V + e.y] = e.x;
        // r >= 48: dropped from sum (degree still counts it) — same safety class as before
    }
    // ---- offs_a[u] = first edge with .x >= u (edges[:,0] sorted asc) ----
    for (int i = t; i <= E; i += T) {
        if (i < E) {
            int lo = (i == 0) ? 0 : edges[i - 1].x + 1;
            int hi = edges[i].x;
            for (int a = lo; a <= hi; ++a) offs_a[a] = i;
        } else {
            int lo = (E > 0) ? edges[E - 1].x + 1 : 0;
            for (int a = lo; a <= V; ++a) offs_a[a] = E;
        }
    }
    // ---- faces -> float (vectorized) ----
    if ((((uintptr_t)out_f | (uintptr_t)faces) & 15) == 0) {
        int n4 = F3 >> 2;
        const int4* f4 = (const int4*)faces;
        float4* o4 = (float4*)out_f;
        for (int j = t; j < n4; j += T) {
            int4 a = f4[j];
            o4[j] = make_float4((float)a.x, (float)a.y, (float)a.z, (float)a.w);
        }
        for (int j = (n4 << 2) + t; j < F3; j += T) out_f[j] = (float)faces[j];
    } else {
        for (int j = t; j < F3; j += T) out_f[j] = (float)faces[j];
    }
    // ---- v[V,3] -> v4[V] float4 repack (vectorized) ----
    if (((uintptr_t)v & 15) == 0) {
        const float4* vv = (const float4*)v;
        int n4v = V >> 2;
        for (int q = t; q < n4v; q += T) {           // 3x float4 in -> 4x out
            float4 a = vv[3 * q], b = vv[3 * q + 1], c = vv[3 * q + 2];
            v4[4 * q + 0] = make_float4(a.x, a.y, a.z, 0.f);
            v4[4 * q + 1] = make_float4(a.w, b.x, b.y, 0.f);
            v4[4 * q + 2] = make_float4(b.z, b.w, c.x, 0.f);
            v4[4 * q + 3] = make_float4(c.y, c.z, c.w, 0.f);
        }
        for (int u = (n4v << 2) + t; u < V; u += T)
            v4[u] = make_float4(v[3 * u], v[3 * u + 1], v[3 * u + 2], 0.f);
    } else {
        for (int u = t; u < V; u += T)
            v4[u] = make_float4(v[3 * u], v[3 * u + 1], v[3 * u + 2], 0.f);
    }
}

// gather: lambd==1 -> y = nbr_sum/deg (deg==0 -> 0, matches ref).
// Single ELL family: metadata = {offs_a pair, cnt} only. 3 latency levels:
// counts -> all index loads (branchless, in-bounds) -> all value loads
// (masked multiply; masked slots clamp to x4[0]/gB[0] = L1-broadcast hits).
template <bool PAD>
__global__ void gather_kernel(const float4* __restrict__ x4, const int2* __restrict__ edges,
                              const int* __restrict__ offs_a, const int* __restrict__ cnt,
                              const int* __restrict__ adj, const int* __restrict__ ovf,
                              float* __restrict__ y, int V, int E) {
    int u = blockIdx.x * blockDim.x + threadIdx.x;
    if (u >= V) return;
    int aBeg = offs_a[u], aEnd = offs_a[u + 1];
    int c = cnt[u];
    int da = aEnd - aBeg;
    int kB = c > K_ELL ? K_ELL : c;
    // ---- level 2: all neighbor-index loads issue together ----
    int gA[UA], gB[UB];
    #pragma unroll
    for (int j = 0; j < UA; ++j) gA[j] = edges[min(aBeg + j, E - 1)].y;  // in-bounds
    #pragma unroll
    for (int k = 0; k < UB; ++k) gB[k] = adj[(size_t)k * V + u];         // coalesced plane read
    // ---- level 3: value loads, mask-multiplied ----
    float s0 = 0.f, s1 = 0.f, s2 = 0.f;
    #pragma unroll
    for (int j = 0; j < UA; ++j) {
        float m = (j < da) ? 1.f : 0.f;              // gA valid vertex id even if j>=da
        float4 p = x4[gA[j]];
        s0 += m * p.x; s1 += m * p.y; s2 += m * p.z;
    }
    for (int j = UA; j < da; ++j) {                  // rare high-valence tail
        float4 p = x4[edges[aBeg + j].y];
        s0 += p.x; s1 += p.y; s2 += p.z;
    }
    #pragma unroll
    for (int k = 0; k < UB; ++k) {
        float m = (k < kB) ? 1.f : 0.f;
        float4 p = x4[(k < kB) ? gB[k] : 0];         // clamp: slot may hold poison
        s0 += m * p.x; s1 += m * p.y; s2 += m * p.z;
    }
    for (int k = UB; k < kB; ++k) {                  // rare tail
        float4 p = x4[adj[(size_t)k * V + u]];
        s0 += p.x; s1 += p.y; s2 += p.z;
    }
    if (c > K_ELL) {                                 // rank overflow (expected never)
        int kO = c - K_ELL; if (kO > K_OVF) kO = K_OVF;
        for (int k = 0; k < kO; ++k) {
            float4 p = x4[ovf[(size_t)k * V + u]];
            s0 += p.x; s1 += p.y; s2 += p.z;
        }
    }
    int d = da + c;
    float inv = 1.0f / fmaxf((float)d, 1.0f);
    if (PAD) {
        ((float4*)y)[u] = make_float4(s0 * inv, s1 * inv, s2 * inv, 0.f);
    } else {
        y[3 * u + 0] = s0 * inv;
        y[3 * u + 1] = s1 * inv;
        y[3 * u + 2] = s2 * inv;
    }
}

extern "C" void kernel_launch(void* const* d_in, const int* in_sizes, int n_in,
                              void* d_out, int out_size, void* d_ws, size_t ws_size,
                              hipStream_t stream) {
    const float* v     = (const float*)d_in[0];  // [V,3]
    const int2*  edges = (const int2*)d_in[1];   // [E,2], rows lex-sorted, a<b
    const int*   faces = (const int*)d_in[2];    // [F,3]

    const int V3 = in_sizes[0];
    const int V  = V3 / 3;
    const int E  = in_sizes[1] / 2;
    const int F3 = in_sizes[2];

    float* out_v = (float*)d_out;
    float* out_f = (float*)d_out + V3;

    // ws layout (16B-aligned float4 arrays first):
    //   v4[V] | x1[V] | adj[K_ELL*V] | ovf[K_OVF*V] | offs_a[V+1] | cnt[V]
    float4* v4     = (float4*)d_ws;
    float4* x1     = v4 + V;
    int*    adj    = (int*)(x1 + V);
    int*    ovf    = adj + (size_t)K_ELL * V;
    int*    offs_a = ovf + (size_t)K_OVF * V;
    int*    cnt    = offs_a + (V + 1);

    // node 1: zero cnt (build's atomic ranks need 0) — 0.75 MB
    (void)hipMemsetAsync(cnt, 0, (size_t)V * sizeof(int), stream);

    // node 2: balanced grid-stride build (scatter + offs_a + faces + v4)
    int maxWork = E + 1;
    if (F3 > maxWork) maxWork = F3;
    if (V > maxWork)  maxWork = V;
    int gB = (maxWork + BB - 1) / BB;
    if (gB > 2048) gB = 2048;
    build_kernel<<<gB, BB, 0, stream>>>(edges, offs_a, cnt, adj, ovf,
                                        faces, out_f, v, v4, E, V, F3);

    // nodes 3+4: two smoothing rounds (plain latency-compressed gather)
    int gV = (V + BS - 1) / BS;
    gather_kernel<true ><<<gV, BS, 0, stream>>>(v4, edges, offs_a, cnt, adj, ovf,
                                                (float*)x1, V, E);
    gather_kernel<false><<<gV, BS, 0, stream>>>(x1, edges, offs_a, cnt, adj, ovf,
                                                out_v, V, E);
}

// Round 7
// 93.410 us; speedup vs baseline: 1.1141x; 1.0391x over previous
//
#include <hip/hip_runtime.h>
#include <stdint.h>

#define K_ELL 32      // ELL planes per near/far array (column-major; untouched planes = 0 traffic)
#define K_OVF 16      // overflow planes (out-of-band fallback, expected ~empty)
#define TBS   1024    // build block size
#define RNG_LOG 11
#define RNG   2048    // build window a-range
#define BAND  2048    // in-band limit on (b - v0 - 1); == RNG so each vertex has unique far owner
#define RW    (RNG + BAND)   // 4096 ints = 16 KB LDS
#define BS    256     // gather block size
#define UA    6       // unrolled a-side slots
#define UN    6       // unrolled near-ELL slots
#define UF    4       // unrolled far-ELL slots

// build: heavy blocks (< NBb) do the b-side transpose via LDS-rank atomics into
// column-major near/far ELL (edge range found by binary search -> no prep
// dependency); copy blocks (>= NBb) do faces->float (int4/float4), v->float4
// repack, offs_a construction, and the cntN[0]/cntF[0..RNG] zeroing — all
// regions disjoint from heavy-block writes. deg_ovf is pre-zeroed by memset.
__global__ __launch_bounds__(TBS) void build_kernel(
        const int2* __restrict__ edges, int* __restrict__ offs_a,
        int* __restrict__ cntN, int* __restrict__ cntF, int* __restrict__ deg_ovf,
        int* __restrict__ adjN, int* __restrict__ adjF, int* __restrict__ adj_ovf,
        const int* __restrict__ faces, float* __restrict__ out_f,
        const float* __restrict__ v, float4* __restrict__ v4,
        int E, int V, int F3, int NBb) {
    if ((int)blockIdx.x >= NBb) {
        int t = (blockIdx.x - NBb) * TBS + threadIdx.x;
        int T = (gridDim.x - NBb) * TBS;
        // ---- faces -> float (vectorized) ----
        if ((((uintptr_t)out_f | (uintptr_t)faces) & 15) == 0) {
            int n4 = F3 >> 2;
            const int4* f4 = (const int4*)faces;
            float4* o4 = (float4*)out_f;
            for (int j = t; j < n4; j += T) {
                int4 a = f4[j];
                o4[j] = make_float4((float)a.x, (float)a.y, (float)a.z, (float)a.w);
            }
            for (int j = (n4 << 2) + t; j < F3; j += T) out_f[j] = (float)faces[j];
        } else {
            for (int j = t; j < F3; j += T) out_f[j] = (float)faces[j];
        }
        // ---- v[V,3] -> v4[V] float4 repack (vectorized) ----
        if (((uintptr_t)v & 15) == 0) {
            const float4* vv = (const float4*)v;
            int n4v = V >> 2;
            for (int q = t; q < n4v; q += T) {       // 3x float4 in -> 4x out
                float4 a = vv[3 * q], b = vv[3 * q + 1], c = vv[3 * q + 2];
                v4[4 * q + 0] = make_float4(a.x, a.y, a.z, 0.f);
                v4[4 * q + 1] = make_float4(a.w, b.x, b.y, 0.f);
                v4[4 * q + 2] = make_float4(b.z, b.w, c.x, 0.f);
                v4[4 * q + 3] = make_float4(c.y, c.z, c.w, 0.f);
            }
            for (int u = (n4v << 2) + t; u < V; u += T)
                v4[u] = make_float4(v[3 * u], v[3 * u + 1], v[3 * u + 2], 0.f);
        } else {
            for (int u = t; u < V; u += T)
                v4[u] = make_float4(v[3 * u], v[3 * u + 1], v[3 * u + 2], 0.f);
        }
        // ---- offs_a[u] = first edge with .x >= u (read only by gather) ----
        for (int i = t; i <= E; i += T) {
            if (i < E) {
                int lo = (i == 0) ? 0 : edges[i - 1].x + 1;
                int hi = edges[i].x;
                for (int a = lo; a <= hi; ++a) offs_a[a] = i;
            } else {
                int lo = (E > 0) ? edges[E - 1].x + 1 : 0;
                for (int a = lo; a <= V; ++a) offs_a[a] = E;
            }
        }
        // ---- zero the counter slots no heavy block dumps (disjoint regions) ----
        for (int i = t; i <= RNG && i < V; i += T) cntF[i] = 0;
        if (t == 0) cntN[0] = 0;
        return;
    }
    __shared__ int cnt[RW];
    __shared__ int s_e[2];
    const int v0   = blockIdx.x << RNG_LOG;
    const int vEnd = min(v0 + RNG, V);
    for (int i = threadIdx.x; i < RW; i += TBS) cnt[i] = 0;
    if (threadIdx.x == 0) {            // lower_bound: first i with edges[i].x >= v0
        int lo = 0, hi = E;
        while (lo < hi) { int mid = (lo + hi) >> 1; if (edges[mid].x < v0) lo = mid + 1; else hi = mid; }
        s_e[0] = lo;
    } else if (threadIdx.x == 64) {    // lower_bound for vEnd (separate wave)
        int lo = 0, hi = E;
        while (lo < hi) { int mid = (lo + hi) >> 1; if (edges[mid].x < vEnd) lo = mid + 1; else hi = mid; }
        s_e[1] = lo;
    }
    __syncthreads();
    const int eBeg = s_e[0];
    const int eEnd = s_e[1];
    for (int i = eBeg + threadIdx.x; i < eEnd; i += TBS) {
        int2 e = edges[i];
        int rel = e.y - (v0 + 1);            // b > a >= v0 -> rel >= 0
        if (rel < RW) {
            int r = atomicAdd(&cnt[rel], 1); // LDS rank = final ELL slot
            if (rel < RNG) { if (r < K_ELL) adjN[(size_t)r * V + e.y] = e.x; }
            else           { if (r < K_ELL) adjF[(size_t)r * V + e.y] = e.x; }
        } else {                              // out-of-band fallback (rare; always correct)
            int r = atomicAdd(&deg_ovf[e.y], 1);
            if (r < K_OVF) adj_ovf[(size_t)r * V + e.y] = e.x;
        }
    }
    __syncthreads();
    for (int i = threadIdx.x; i < RW; i += TBS) {
        int u = v0 + 1 + i;
        if (u < V) {
            if (i < RNG) cntN[u] = cnt[i];   // unique near owner (u's own window)
            else         cntF[u] = cnt[i];   // unique far owner (previous window)
        }
    }
}

// gather: lambd==1 -> y = nbr_sum/deg (deg==0 -> 0, matches ref).
// 3 latency levels: counts/offsets -> all index loads (branchless, in-bounds)
// -> all value loads. ALL masked slots clamp to index 0 (wave-broadcast line,
// ~free) — including a-side, which previously fetched a real divergent line.
// Masked lanes add m*p = +0.0 -> bit-exact, accumulation order preserved.
template <bool PAD>
__global__ void gather_kernel(const float4* __restrict__ x4, const int2* __restrict__ edges,
                              const int* __restrict__ offs_a,
                              const int* __restrict__ cntN, const int* __restrict__ cntF,
                              const int* __restrict__ deg_ovf,
                              const int* __restrict__ adjN, const int* __restrict__ adjF,
                              const int* __restrict__ adj_ovf,
                              float* __restrict__ y, int V, int E) {
    int u = blockIdx.x * blockDim.x + threadIdx.x;
    if (u >= V) return;
    int aBeg = offs_a[u], aEnd = offs_a[u + 1];
    int cN = cntN[u], cF = cntF[u], dO = deg_ovf[u];
    int da = aEnd - aBeg;
    int kN = cN > K_ELL ? K_ELL : cN;
    int kF = cF > K_ELL ? K_ELL : cF;
    // ---- level 2: all neighbor-index loads issue together ----
    int gA[UA], gN[UN], gF[UF];
    #pragma unroll
    for (int j = 0; j < UA; ++j) gA[j] = edges[min(aBeg + j, E - 1)].y;  // in-bounds
    #pragma unroll
    for (int k = 0; k < UN; ++k) gN[k] = adjN[(size_t)k * V + u];        // coalesced plane reads
    #pragma unroll
    for (int k = 0; k < UF; ++k) gF[k] = adjF[(size_t)k * V + u];
    // ---- level 3: value loads, mask-multiplied ----
    float s0 = 0.f, s1 = 0.f, s2 = 0.f;
    #pragma unroll
    for (int j = 0; j < UA; ++j) {
        float m = (j < da) ? 1.f : 0.f;
        float4 p = x4[(j < da) ? gA[j] : 0];           // masked -> broadcast line
        s0 += m * p.x; s1 += m * p.y; s2 += m * p.z;
    }
    for (int j = UA; j < da; ++j) {                    // rare high-valence tail
        float4 p = x4[edges[aBeg + j].y];
        s0 += p.x; s1 += p.y; s2 += p.z;
    }
    #pragma unroll
    for (int k = 0; k < UN; ++k) {
        float m = (k < kN) ? 1.f : 0.f;
        float4 p = x4[(k < kN) ? gN[k] : 0];
        s0 += m * p.x; s1 += m * p.y; s2 += m * p.z;
    }
    for (int k = UN; k < kN; ++k) {
        float4 p = x4[adjN[(size_t)k * V + u]];
        s0 += p.x; s1 += p.y; s2 += p.z;
    }
    #pragma unroll
    for (int k = 0; k < UF; ++k) {
        float m = (k < kF) ? 1.f : 0.f;
        float4 p = x4[(k < kF) ? gF[k] : 0];
        s0 += m * p.x; s1 += m * p.y; s2 += m * p.z;
    }
    for (int k = UF; k < kF; ++k) {
        float4 p = x4[adjF[(size_t)k * V + u]];
        s0 += p.x; s1 += p.y; s2 += p.z;
    }
    int kO = dO > K_OVF ? K_OVF : dO;
    for (int k = 0; k < kO; ++k) {                     // expected empty
        float4 p = x4[adj_ovf[(size_t)k * V + u]];
        s0 += p.x; s1 += p.y; s2 += p.z;
    }
    int d = da + cN + cF + dO;
    float inv = 1.0f / fmaxf((float)d, 1.0f);
    if (PAD) {
        ((float4*)y)[u] = make_float4(s0 * inv, s1 * inv, s2 * inv, 0.f);
    } else {
        y[3 * u + 0] = s0 * inv;
        y[3 * u + 1] = s1 * inv;
        y[3 * u + 2] = s2 * inv;
    }
}

extern "C" void kernel_launch(void* const* d_in, const int* in_sizes, int n_in,
                              void* d_out, int out_size, void* d_ws, size_t ws_size,
                              hipStream_t stream) {
    const float* v     = (const float*)d_in[0];  // [V,3]
    const int2*  edges = (const int2*)d_in[1];   // [E,2], rows lex-sorted, a<b
    const int*   faces = (const int*)d_in[2];    // [F,3]

    const int V3 = in_sizes[0];
    const int V  = V3 / 3;
    const int E  = in_sizes[1] / 2;
    const int F3 = in_sizes[2];

    float* out_v = (float*)d_out;
    float* out_f = (float*)d_out + V3;

    // ws layout (16B-aligned float4 arrays first): v4[V] | x1[V] | adjN[K_ELL*V] |
    //   adjF[K_ELL*V] | adj_ovf[K_OVF*V] | offs_a[V+1] | cntN[V+1] | cntF[V+1] | deg_ovf[V]
    float4* v4      = (float4*)d_ws;
    float4* x1      = v4 + V;
    int*    adjN    = (int*)(x1 + V);
    int*    adjF    = adjN + (size_t)K_ELL * V;
    int*    adj_ovf = adjF + (size_t)K_ELL * V;
    int*    offs_a  = adj_ovf + (size_t)K_OVF * V;
    int*    cntN    = offs_a + (V + 1);
    int*    cntF    = cntN + (V + 1);
    int*    deg_ovf = cntF + (V + 1);

    const int NBb = (V + RNG - 1) / RNG;          // heavy build blocks (~91)
    const int copyElems = F3 > V ? F3 : V;
    const int NBc = (copyElems + TBS - 1) / TBS;  // copy blocks (~1086)
    const int gV  = (V + BS - 1) / BS;

    // node 1: zero deg_ovf (build's out-of-band atomics need 0) — 0.75 MB fill
    (void)hipMemsetAsync(deg_ovf, 0, (size_t)V * sizeof(int), stream);

    // node 2: build (heavy windows via binary-search range + copy/prep work)
    build_kernel<<<NBb + NBc, TBS, 0, stream>>>(edges, offs_a, cntN, cntF, deg_ovf,
                                                adjN, adjF, adj_ovf, faces, out_f,
                                                v, v4, E, V, F3, NBb);

    // nodes 3+4: two smoothing rounds
    gather_kernel<true ><<<gV, BS, 0, stream>>>(v4, edges, offs_a, cntN, cntF, deg_ovf,
                                                adjN, adjF, adj_ovf, (float*)x1, V, E);
    gather_kernel<false><<<gV, BS, 0, stream>>>(x1, edges, offs_a, cntN, cntF, deg_ovf,
                                                adjN, adjF, adj_ovf, out_v, V, E);
}

// Round 8
// 85.539 us; speedup vs baseline: 1.2166x; 1.0920x over previous
//
#include <hip/hip_runtime.h>
#include <stdint.h>

#define K_ELL 32      // ELL planes per near/far array (column-major; untouched planes = 0 traffic)
#define K_OVF 16      // overflow planes (out-of-band fallback, expected ~empty)
#define TBS   1024    // build block size
#define RNG_LOG 11
#define RNG   2048    // build block a-range
#define BAND  2048    // in-band limit on (b - v0 - 1); == RNG so each vertex has unique far owner
#define RW    (RNG + BAND)   // 4096 ints = 16 KB LDS
#define BS    256
#define UA    6       // unrolled a-side slots
#define UN    6       // unrolled near-ELL slots
#define UF    4       // unrolled far-ELL slots
#define NXCD  8

// bijective XCD-aware swizzle (m204): blocks with the same hw id % 8 (same XCD)
// get a CONTIGUOUS range of logical block ids -> each XCD owns one vertex band.
__device__ __forceinline__ int xcd_swz(int bid, int nwg) {
    int q = nwg >> 3, r = nwg & 7;
    int x = bid & 7, idx = bid >> 3;
    return (x < r ? x * (q + 1) : r * (q + 1) + (x - r) * q) + idx;
}

// prep (light): offs_a[u] = first edge index with edges[.].x >= u (edges[:,0]
// sorted asc, a<b); zero the counters build's LDS dumps don't cover.
__global__ void prep_kernel(const int2* __restrict__ edges, int* __restrict__ offs_a,
                            int* __restrict__ cntN, int* __restrict__ cntF,
                            int* __restrict__ deg_ovf, int E, int V) {
    int i = blockIdx.x * blockDim.x + threadIdx.x;
    if (i <= E) {
        if (i < E) {
            int lo = (i == 0) ? 0 : edges[i - 1].x + 1;
            int hi = edges[i].x;
            for (int a = lo; a <= hi; a++) offs_a[a] = i;
        } else {
            for (int a = edges[E - 1].x + 1; a <= V; a++) offs_a[a] = E;
        }
    }
    if (i < V) deg_ovf[i] = 0;
    if (i <= RNG) cntF[i] = 0;   // vertices with no far-owner block
    if (i == 0) cntN[0] = 0;     // vertex 0 has no near-owner block
}

// build: heavy blocks (< NBb) do the b-side transpose via LDS-rank atomics into
// column-major near/far ELL; copy blocks (>= NBb) do faces->float (vectorized)
// and v->float4 repack on the ~165 CUs the heavy blocks leave idle.
__global__ __launch_bounds__(TBS) void build_kernel(
        const int2* __restrict__ edges, const int* __restrict__ offs_a,
        int* __restrict__ cntN, int* __restrict__ cntF, int* __restrict__ deg_ovf,
        int* __restrict__ adjN, int* __restrict__ adjF, int* __restrict__ adj_ovf,
        const int* __restrict__ faces, float* __restrict__ out_f,
        const float* __restrict__ v, float4* __restrict__ v4,
        int E, int V, int F3, int NBb) {
    if ((int)blockIdx.x >= NBb) {
        int t = (blockIdx.x - NBb) * TBS + threadIdx.x;
        int T = (gridDim.x - NBb) * TBS;
        if ((((uintptr_t)out_f | (uintptr_t)faces) & 15) == 0) {
            int n4 = F3 >> 2;
            const int4* f4 = (const int4*)faces;
            float4* o4 = (float4*)out_f;
            for (int j = t; j < n4; j += T) {
                int4 a = f4[j];
                o4[j] = make_float4((float)a.x, (float)a.y, (float)a.z, (float)a.w);
            }
            for (int j = (n4 << 2) + t; j < F3; j += T) out_f[j] = (float)faces[j];
        } else {
            for (int j = t; j < F3; j += T) out_f[j] = (float)faces[j];
        }
        if (((uintptr_t)v & 15) == 0) {
            const float4* vv = (const float4*)v;
            int n4v = V >> 2;
            for (int q = t; q < n4v; q += T) {   // 3x float4 in -> 4x float4 out
                float4 a = vv[3 * q], b = vv[3 * q + 1], c = vv[3 * q + 2];
                v4[4 * q + 0] = make_float4(a.x, a.y, a.z, 0.f);
                v4[4 * q + 1] = make_float4(a.w, b.x, b.y, 0.f);
                v4[4 * q + 2] = make_float4(b.z, b.w, c.x, 0.f);
                v4[4 * q + 3] = make_float4(c.y, c.z, c.w, 0.f);
            }
            for (int u = (n4v << 2) + t; u < V; u += T)
                v4[u] = make_float4(v[3 * u], v[3 * u + 1], v[3 * u + 2], 0.f);
        } else {
            for (int u = t; u < V; u += T)
                v4[u] = make_float4(v[3 * u], v[3 * u + 1], v[3 * u + 2], 0.f);
        }
        return;
    }
    __shared__ int cnt[RW];
    const int v0   = blockIdx.x << RNG_LOG;
    const int vEnd = min(v0 + RNG, V);
    for (int i = threadIdx.x; i < RW; i += TBS) cnt[i] = 0;
    const int eBeg = offs_a[v0];
    const int eEnd = offs_a[vEnd];
    __syncthreads();
    for (int i = eBeg + threadIdx.x; i < eEnd; i += TBS) {
        int2 e = edges[i];
        int rel = e.y - (v0 + 1);            // b > a >= v0 -> rel >= 0
        if (rel < RW) {
            int r = atomicAdd(&cnt[rel], 1); // LDS rank = final ELL slot
            if (rel < RNG) { if (r < K_ELL) adjN[(size_t)r * V + e.y] = e.x; }
            else           { if (r < K_ELL) adjF[(size_t)r * V + e.y] = e.x; }
        } else {                              // out-of-band fallback (rare; always correct)
            int r = atomicAdd(&deg_ovf[e.y], 1);
            if (r < K_OVF) adj_ovf[(size_t)r * V + e.y] = e.x;
        }
    }
    __syncthreads();
    for (int i = threadIdx.x; i < RW; i += TBS) {
        int u = v0 + 1 + i;
        if (u < V) {
            if (i < RNG) cntN[u] = cnt[i];   // unique near owner
            else         cntF[u] = cnt[i];   // unique far owner (BAND == RNG)
        }
    }
}

// gather: lambd==1 -> y = nbr_sum/deg (deg==0 -> 0, matches ref).
// XCD-swizzled: each XCD owns a contiguous vertex band -> x4/x1 band stays in
// that XCD's L2 across both rounds (no 8x cross-XCD refetch). 3 latency
// levels; ALL masked slots clamp to index 0 (wave-broadcast line, ~free).
// Masked lanes add m*p = +0.0 -> bit-exact, accumulation order preserved.
template <bool PAD>
__global__ void gather_kernel(const float4* __restrict__ x4, const int2* __restrict__ edges,
                              const int* __restrict__ offs_a,
                              const int* __restrict__ cntN, const int* __restrict__ cntF,
                              const int* __restrict__ deg_ovf,
                              const int* __restrict__ adjN, const int* __restrict__ adjF,
                              const int* __restrict__ adj_ovf,
                              float* __restrict__ y, int V, int E) {
    int u = xcd_swz((int)blockIdx.x, (int)gridDim.x) * BS + (int)threadIdx.x;
    if (u >= V) return;
    int aBeg = offs_a[u], aEnd = offs_a[u + 1];
    int cN = cntN[u], cF = cntF[u], dO = deg_ovf[u];
    int da = aEnd - aBeg;
    int kN = cN > K_ELL ? K_ELL : cN;
    int kF = cF > K_ELL ? K_ELL : cF;
    // ---- level 2: all neighbor-index loads issue together ----
    int gA[UA], gN[UN], gF[UF];
    #pragma unroll
    for (int j = 0; j < UA; ++j) gA[j] = edges[min(aBeg + j, E - 1)].y;  // in-bounds
    #pragma unroll
    for (int k = 0; k < UN; ++k) gN[k] = adjN[(size_t)k * V + u];        // coalesced plane reads
    #pragma unroll
    for (int k = 0; k < UF; ++k) gF[k] = adjF[(size_t)k * V + u];
    // ---- level 3: value loads, mask-multiplied ----
    float s0 = 0.f, s1 = 0.f, s2 = 0.f;
    #pragma unroll
    for (int j = 0; j < UA; ++j) {
        float m = (j < da) ? 1.f : 0.f;
        float4 p = x4[(j < da) ? gA[j] : 0];           // masked -> broadcast line
        s0 += m * p.x; s1 += m * p.y; s2 += m * p.z;
    }
    for (int j = UA; j < da; ++j) {                    // rare high-valence tail
        float4 p = x4[edges[aBeg + j].y];
        s0 += p.x; s1 += p.y; s2 += p.z;
    }
    #pragma unroll
    for (int k = 0; k < UN; ++k) {
        float m = (k < kN) ? 1.f : 0.f;
        float4 p = x4[(k < kN) ? gN[k] : 0];
        s0 += m * p.x; s1 += m * p.y; s2 += m * p.z;
    }
    for (int k = UN; k < kN; ++k) {
        float4 p = x4[adjN[(size_t)k * V + u]];
        s0 += p.x; s1 += p.y; s2 += p.z;
    }
    #pragma unroll
    for (int k = 0; k < UF; ++k) {
        float m = (k < kF) ? 1.f : 0.f;
        float4 p = x4[(k < kF) ? gF[k] : 0];
        s0 += m * p.x; s1 += m * p.y; s2 += m * p.z;
    }
    for (int k = UF; k < kF; ++k) {
        float4 p = x4[adjF[(size_t)k * V + u]];
        s0 += p.x; s1 += p.y; s2 += p.z;
    }
    int kO = dO > K_OVF ? K_OVF : dO;
    for (int k = 0; k < kO; ++k) {                     // expected empty
        float4 p = x4[adj_ovf[(size_t)k * V + u]];
        s0 += p.x; s1 += p.y; s2 += p.z;
    }
    int d = da + cN + cF + dO;
    float inv = 1.0f / fmaxf((float)d, 1.0f);
    if (PAD) {
        ((float4*)y)[u] = make_float4(s0 * inv, s1 * inv, s2 * inv, 0.f);
    } else {
        y[3 * u + 0] = s0 * inv;
        y[3 * u + 1] = s1 * inv;
        y[3 * u + 2] = s2 * inv;
    }
}

extern "C" void kernel_launch(void* const* d_in, const int* in_sizes, int n_in,
                              void* d_out, int out_size, void* d_ws, size_t ws_size,
                              hipStream_t stream) {
    const float* v     = (const float*)d_in[0];  // [V,3]
    const int2*  edges = (const int2*)d_in[1];   // [E,2], rows lex-sorted, a<b
    const int*   faces = (const int*)d_in[2];    // [F,3]

    const int V3 = in_sizes[0];
    const int V  = V3 / 3;
    const int E  = in_sizes[1] / 2;
    const int F3 = in_sizes[2];

    float* out_v = (float*)d_out;
    float* out_f = (float*)d_out + V3;

    // ws layout (16B-aligned float4 arrays first): v4[V] | x1[V] | adjN[K_ELL*V] |
    //   adjF[K_ELL*V] | adj_ovf[K_OVF*V] | offs_a[V+1] | cntN[V+1] | cntF[V+1] | deg_ovf[V]
    float4* v4      = (float4*)d_ws;
    float4* x1      = v4 + V;
    int*    adjN    = (int*)(x1 + V);
    int*    adjF    = adjN + (size_t)K_ELL * V;
    int*    adj_ovf = adjF + (size_t)K_ELL * V;
    int*    offs_a  = adj_ovf + (size_t)K_OVF * V;
    int*    cntN    = offs_a + (V + 1);
    int*    cntF    = cntN + (V + 1);
    int*    deg_ovf = cntF + (V + 1);

    const int NBb = (V + RNG - 1) / RNG;          // heavy build blocks (~91)
    const int copyElems = F3 > V ? F3 : V;
    const int NBc = (copyElems + TBS - 1) / TBS;  // copy blocks (~1086)
    const int gP  = (E + 1 + BS - 1) / BS;        // prep covers edges (+V zeroing folded)
    const int gV  = (V + BS - 1) / BS;

    prep_kernel<<<gP, BS, 0, stream>>>(edges, offs_a, cntN, cntF, deg_ovf, E, V);

    build_kernel<<<NBb + NBc, TBS, 0, stream>>>(edges, offs_a, cntN, cntF, deg_ovf,
                                                adjN, adjF, adj_ovf, faces, out_f,
                                                v, v4, E, V, F3, NBb);

    gather_kernel<true ><<<gV, BS, 0, stream>>>(v4, edges, offs_a, cntN, cntF, deg_ovf,
                                                adjN, adjF, adj_ovf, (float*)x1, V, E);
    gather_kernel<false><<<gV, BS, 0, stream>>>(x1, edges, offs_a, cntN, cntF, deg_ovf,
                                                adjN, adjF, adj_ovf, out_v, V, E);
}